// Round 4
// baseline (912.780 us; speedup 1.0000x reference)
//
#include <hip/hip_runtime.h>

typedef __attribute__((ext_vector_type(8))) short bf16x8;
typedef __attribute__((ext_vector_type(4))) float f32x4;

static __device__ __forceinline__ unsigned short f2bf(float f) {
    union { float f; unsigned u; } v; v.f = f;
    return (unsigned short)((v.u + 0x7FFFu + ((v.u >> 16) & 1u)) >> 16);
}

// Wp[ch=4][rs=9][oc=256][cw=32] bf16, value = weight[oc][ch*32+cw][r][s] * wscale
__global__ void prep_weights(const float* __restrict__ w, unsigned short* __restrict__ wp) {
    int t = blockIdx.x * 256 + threadIdx.x;      // 0..294911
    const float wscale = 0.02946278254943948f;   // 1/sqrt(3*3*128)
    int cw = t & 31;
    int oc = (t >> 5) & 255;
    int cr = t >> 13;          // 0..35
    int ch = cr / 9;
    int rs = cr - ch * 9;
    int r  = rs / 3;
    int s  = rs - r * 3;
    int c  = ch * 32 + cw;
    wp[t] = f2bf(w[((oc * 128 + c) * 3 + r) * 3 + s] * wscale);
}

// guarded 16B window load for 2 channel planes (window start global col = wcol)
#define XLOAD(PP0, PP1, xrr) do {                                              \
    int _xr = (xrr);                                                           \
    if ((unsigned)_xr < 256u) {                                                \
        const float* _r0 = q0 + (_xr << 8);                                    \
        const float* _r1 = _r0 + 65536;                                        \
        if (colok) {                                                           \
            __builtin_memcpy(&PP0, _r0, 16); __builtin_memcpy(&PP1, _r1, 16);  \
        } else {                                                               \
            f32x4 _t0 = {0.f,0.f,0.f,0.f}, _t1 = {0.f,0.f,0.f,0.f};            \
            if ((unsigned)(wcol + 0) < 256u) { _t0.x = _r0[0]; _t1.x = _r1[0]; } \
            if ((unsigned)(wcol + 1) < 256u) { _t0.y = _r0[1]; _t1.y = _r1[1]; } \
            if ((unsigned)(wcol + 2) < 256u) { _t0.z = _r0[2]; _t1.z = _r1[2]; } \
            if ((unsigned)(wcol + 3) < 256u) { _t0.w = _r0[3]; _t1.w = _r1[3]; } \
            PP0 = _t0; PP1 = _t1;                                              \
        }                                                                      \
    } else { PP0 = (f32x4){0.f,0.f,0.f,0.f}; PP1 = (f32x4){0.f,0.f,0.f,0.f}; } \
} while (0)

// wg: 512 thr = 8 waves (2m x 4n), tile = 8h x 16w out pixels x 256 oc.
// Blurred tile in LDS: [bi=17][bj=33] pixels, 80 B/pixel (4 x 16B ch-slots, XOR-swizzled).
__global__ __launch_bounds__(512, 4)
void conv_blur_mfma(const float* __restrict__ x, const unsigned short* __restrict__ wp,
                    const float* __restrict__ bias, float* __restrict__ out) {
    __shared__ __align__(16) unsigned char lds[17 * 33 * 80];   // 44880 B

    const int bx = blockIdx.x;
    const int n  = bx >> 7;          // image
    const int tt = bx & 127;
    const int u0 = (tt >> 3) * 8;    // out-row origin
    const int v0 = (tt & 7) * 16;    // out-col origin

    const int tid  = threadIdx.x;
    const int lane = tid & 63;
    const int wid  = tid >> 6;
    const int wm   = wid >> 2;       // 0..1 : pixel-row block
    const int wn   = wid & 3;        // 0..3 : oc block
    const int g    = lane >> 4;      // 0..3 : k-group
    const int wq   = lane & 15;

    // blur item: ch-pair cpi, column col (0..31); col 32 handled by mini-phase
    const int col  = tid & 31;
    const int cpi  = tid >> 5;       // 0..15
    const int wcol = 2 * v0 - 2 + col;                 // global x col of window start
    const bool colok = ((unsigned)wcol <= 252u);
    const float* xplane0 = x + (size_t)(n * 128 + 2 * cpi) * 65536 + wcol;
    // blurred-tile write offset (row 0), swizzled slot
    const unsigned vboff = (unsigned)col * 80u
                         + ((unsigned)((cpi >> 2) ^ ((col >> 3) & 3)) << 4)
                         + (unsigned)(cpi & 3) * 4u;
    const int xr0 = 2 * u0 - 2;

    // weights pointer (verified layout)
    const unsigned short* wpL = wp + (size_t)(wn * 64 + wq) * 32 + g * 8;

    f32x4 acc[4][4];
    #pragma unroll
    for (int i = 0; i < 4; ++i)
        #pragma unroll
        for (int j = 0; j < 4; ++j)
            acc[i][j] = (f32x4){0.f, 0.f, 0.f, 0.f};

    for (int ch = 0; ch < 4; ++ch) {
        const float* q0 = xplane0 + (size_t)ch * 32 * 65536;
        // prologue: fill 4 pipeline slots (rows for s=0..3), before the barrier
        f32x4 pa0, pa1, pb0, pb1, pc0, pc1, pd0, pd1;
        XLOAD(pa0, pa1, xr0 + 0);
        XLOAD(pb0, pb1, xr0 + 1);
        XLOAD(pc0, pc1, xr0 + 2);
        XLOAD(pd0, pd1, xr0 + 3);
        __syncthreads();   // prev chunk's MFMA reads done before we overwrite blurred
        float h0[20], h1[20];
        #pragma unroll
        for (int s = 0; s < 20; ++s) {
            f32x4 c0, c1;
            if ((s & 3) == 0)      { c0 = pa0; c1 = pa1; }
            else if ((s & 3) == 1) { c0 = pb0; c1 = pb1; }
            else if ((s & 3) == 2) { c0 = pc0; c1 = pc1; }
            else                   { c0 = pd0; c1 = pd1; }
            h0[s] = (c0.x + 3.f * (c0.y + c0.z) + c0.w) * 0.125f;
            h1[s] = (c1.x + 3.f * (c1.y + c1.z) + c1.w) * 0.125f;
            if (s < 16) {          // prefetch row for step s+4 into the slot just consumed
                int xr = xr0 + 4 + s;
                if ((s & 3) == 0)      XLOAD(pa0, pa1, xr);
                else if ((s & 3) == 1) XLOAD(pb0, pb1, xr);
                else if ((s & 3) == 2) XLOAD(pc0, pc1, xr);
                else                   XLOAD(pd0, pd1, xr);
            }
            if (s >= 3) {
                float bv0 = (h0[s-3] + 3.f * (h0[s-2] + h0[s-1]) + h0[s]) * 0.125f;
                float bv1 = (h1[s-3] + 3.f * (h1[s-2] + h1[s-1]) + h1[s]) * 0.125f;
                unsigned pk = (unsigned)f2bf(bv0) | ((unsigned)f2bf(bv1) << 16);
                *(unsigned*)(lds + (unsigned)(s - 3) * 2640u + vboff) = pk;
            }
        }
        // ---- mini-phase: column 32 (16 ch-pairs x 17 rows = 272 items) ----
        if (tid < 272) {
            int cp32 = tid / 17;
            int bi32 = tid - cp32 * 17;
            int w32  = 2 * v0 + 30;
            const float* p0 = x + (size_t)(n * 128 + ch * 32 + 2 * cp32) * 65536 + w32;
            float s0 = 0.f, s1 = 0.f;
            #pragma unroll
            for (int p = 0; p < 4; ++p) {
                int xr = 2 * u0 + bi32 - 2 + p;
                if ((unsigned)xr < 256u) {
                    const float* r0 = p0 + (xr << 8);
                    const float* r1 = r0 + 65536;
                    float e00=0.f,e01=0.f,e02=0.f,e03=0.f,e10=0.f,e11=0.f,e12=0.f,e13=0.f;
                    if ((unsigned)(w32 + 0) < 256u) { e00 = r0[0]; e10 = r1[0]; }
                    if ((unsigned)(w32 + 1) < 256u) { e01 = r0[1]; e11 = r1[1]; }
                    if ((unsigned)(w32 + 2) < 256u) { e02 = r0[2]; e12 = r1[2]; }
                    if ((unsigned)(w32 + 3) < 256u) { e03 = r0[3]; e13 = r1[3]; }
                    float hh0 = (e00 + 3.f * (e01 + e02) + e03) * 0.125f;
                    float hh1 = (e10 + 3.f * (e11 + e12) + e13) * 0.125f;
                    float fw = (p == 0 || p == 3) ? 0.125f : 0.375f;
                    s0 += fw * hh0; s1 += fw * hh1;
                }
            }
            unsigned pk = (unsigned)f2bf(s0) | ((unsigned)f2bf(s1) << 16);
            *(unsigned*)(lds + ((unsigned)bi32 * 33u + 32u) * 80u
                             + ((unsigned)(cp32 >> 2) << 4) + (unsigned)(cp32 & 3) * 4u) = pk;
        }
        __syncthreads();   // blurred tile complete
        // ---- MFMA stage: 3x3 taps, unroll 1 to cap live registers ----
        const unsigned short* wpc = wpL + (size_t)ch * 9 * 8192;
        #pragma unroll 1
        for (int r = 0; r < 3; ++r) {
            #pragma unroll 1
            for (int s = 0; s < 3; ++s) {
                bf16x8 b0 = *(const bf16x8*)(wpc + 0 * 512);
                bf16x8 b1 = *(const bf16x8*)(wpc + 1 * 512);
                bf16x8 b2 = *(const bf16x8*)(wpc + 2 * 512);
                bf16x8 b3 = *(const bf16x8*)(wpc + 3 * 512);
                wpc += 8192;
                int bj = 2 * wq + s;
                unsigned cb = (unsigned)bj * 80u
                            + ((unsigned)(g ^ ((bj >> 3) & 3)) << 4);
                #pragma unroll
                for (int mf = 0; mf < 4; ++mf) {
                    int bi = 2 * (wm * 4 + mf) + r;
                    bf16x8 afrag = *(const bf16x8*)(lds + (unsigned)bi * 2640u + cb);
                    acc[mf][0] = __builtin_amdgcn_mfma_f32_16x16x32_bf16(afrag, b0, acc[mf][0], 0, 0, 0);
                    acc[mf][1] = __builtin_amdgcn_mfma_f32_16x16x32_bf16(afrag, b1, acc[mf][1], 0, 0, 0);
                    acc[mf][2] = __builtin_amdgcn_mfma_f32_16x16x32_bf16(afrag, b2, acc[mf][2], 0, 0, 0);
                    acc[mf][3] = __builtin_amdgcn_mfma_f32_16x16x32_bf16(afrag, b3, acc[mf][3], 0, 0, 0);
                }
            }
        }
    }

    // ---- epilogue: direct coalesced stores (u = u0+wm*4+mf, v = v0+4g+i, oc = wn*64+nf*16+wq) ----
    const float gain = 1.4142135623730951f;   // sqrt(2)
    #pragma unroll
    for (int nf = 0; nf < 4; ++nf) {
        int ocg = wn * 64 + nf * 16 + wq;
        float bv = bias[ocg];                 // LR_MUL = 1
        #pragma unroll
        for (int mf = 0; mf < 4; ++mf) {
            int u = u0 + wm * 4 + mf;
            f32x4 o;
            #pragma unroll
            for (int i = 0; i < 4; ++i) {
                float z = acc[mf][nf][i] + bv;
                z = (z >= 0.f ? z : 0.2f * z) * gain;
                o[i] = fminf(fmaxf(z, -256.f), 256.f);
            }
            *(f32x4*)(out + (((size_t)n * 256 + ocg) * 128 + u) * 128 + v0 + 4 * g) = o;
        }
    }
}

extern "C" void kernel_launch(void* const* d_in, const int* in_sizes, int n_in,
                              void* d_out, int out_size, void* d_ws, size_t ws_size,
                              hipStream_t stream) {
    const float* x    = (const float*)d_in[0];
    const float* w    = (const float*)d_in[1];
    const float* bias = (const float*)d_in[2];
    unsigned short* wp = (unsigned short*)d_ws;   // 589,824 B
    float* out = (float*)d_out;

    prep_weights<<<1152, 256, 0, stream>>>(w, wp);
    conv_blur_mfma<<<2048, 512, 0, stream>>>(x, wp, bias, out);
}

// Round 5
// 483.480 us; speedup vs baseline: 1.8879x; 1.8879x over previous
//
#include <hip/hip_runtime.h>

typedef __attribute__((ext_vector_type(8))) short bf16x8;
typedef __attribute__((ext_vector_type(4))) float f32x4;
typedef __attribute__((ext_vector_type(2))) float f32x2;

static __device__ __forceinline__ unsigned short f2bf(float f) {
    union { float f; unsigned u; } v; v.f = f;
    return (unsigned short)((v.u + 0x7FFFu + ((v.u >> 16) & 1u)) >> 16);
}

// Wp[ch=4][rs=9][oc=256][cw=32] bf16, value = weight[oc][ch*32+cw][r][s] * wscale
__global__ void prep_weights(const float* __restrict__ w, unsigned short* __restrict__ wp) {
    int t = blockIdx.x * 256 + threadIdx.x;      // 0..294911
    const float wscale = 0.02946278254943948f;   // 1/sqrt(3*3*128)
    int cw = t & 31;
    int oc = (t >> 5) & 255;
    int cr = t >> 13;          // 0..35
    int ch = cr / 9;
    int rs = cr - ch * 9;
    int r  = rs / 3;
    int s  = rs - r * 3;
    int c  = ch * 32 + cw;
    wp[t] = f2bf(w[((oc * 128 + c) * 3 + r) * 3 + s] * wscale);
}

// fast row: unconditional 24B load (row-clamped), validity folded into scale
#define FROW(row) {                                                            \
    int xr  = xr0 + (row);                                                     \
    int xrc = xr < 0 ? 0 : (xr > 255 ? 255 : xr);                              \
    float rm = (xr == xrc) ? 0.125f : 0.0f;                                    \
    const float* p = q + (xrc << 8);                                           \
    f32x4 lo; f32x2 hi;                                                        \
    __builtin_memcpy(&lo, p, 16);                                              \
    __builtin_memcpy(&hi, p + 4, 8);                                           \
    hA[(row) & 3] = (lo.x + 3.f * (lo.y + lo.z) + lo.w) * rm;                  \
    hB[(row) & 3] = (lo.y + 3.f * (lo.z + lo.w) + hi.x) * rm;                  \
    hC[(row) & 3] = (lo.z + 3.f * (lo.w + hi.x) + hi.y) * rm;                  \
}

// slow row (edge lanes only): per-element guarded loads
#define SROW(row) {                                                            \
    int xr = xr0 + (row);                                                      \
    float wv0=0.f,wv1=0.f,wv2=0.f,wv3=0.f,wv4=0.f,wv5=0.f;                     \
    if ((unsigned)xr < 256u) {                                                 \
        const float* p = q + (xr << 8);                                        \
        if ((unsigned)(wc + 0) < 256u) wv0 = p[0];                             \
        if ((unsigned)(wc + 1) < 256u) wv1 = p[1];                             \
        if ((unsigned)(wc + 2) < 256u) wv2 = p[2];                             \
        if ((unsigned)(wc + 3) < 256u) wv3 = p[3];                             \
        if ((unsigned)(wc + 4) < 256u) wv4 = p[4];                             \
        if ((unsigned)(wc + 5) < 256u) wv5 = p[5];                             \
    }                                                                          \
    hA[(row) & 3] = (wv0 + 3.f * (wv1 + wv2) + wv3) * 0.125f;                  \
    hB[(row) & 3] = (wv1 + 3.f * (wv2 + wv3) + wv4) * 0.125f;                  \
    hC[(row) & 3] = (wv2 + 3.f * (wv3 + wv4) + wv5) * 0.125f;                  \
}

// vertical blur + LDS writes (blurred row = row-3)
#define VROW(row) {                                                            \
    float bv0 = (hA[(row - 3) & 3] + 3.f * (hA[(row - 2) & 3] + hA[(row - 1) & 3]) + hA[(row) & 3]) * 0.125f; \
    float bv1 = (hB[(row - 3) & 3] + 3.f * (hB[(row - 2) & 3] + hB[(row - 1) & 3]) + hB[(row) & 3]) * 0.125f; \
    unsigned rb = (unsigned)(row - 3) * 2640u;                                 \
    *(unsigned short*)(lds + rb + o0) = f2bf(bv0);                             \
    *(unsigned short*)(lds + rb + o1) = f2bf(bv1);                             \
    if (a == 15) {                                                             \
        float bv2 = (hC[(row - 3) & 3] + 3.f * (hC[(row - 2) & 3] + hC[(row - 1) & 3]) + hC[(row) & 3]) * 0.125f; \
        *(unsigned short*)(lds + rb + o2) = f2bf(bv2);                         \
    }                                                                          \
}

// wg: 512 thr = 8 waves (2m x 4n), tile = 8h x 16w out pixels x 256 oc.
// Blurred tile in LDS: [bi=17][bj=33] px, 80 B/px (5 x 16B ch-slots, XOR-swizzled).
__global__ __launch_bounds__(512, 4)
void conv_blur_mfma(const float* __restrict__ x, const unsigned short* __restrict__ wp,
                    const float* __restrict__ bias, float* __restrict__ out) {
    __shared__ __align__(16) unsigned char lds[17 * 33 * 80];   // 44880 B

    const int bx = blockIdx.x;
    const int n  = bx >> 7;          // image
    const int tt = bx & 127;
    const int u0 = (tt >> 3) * 8;    // out-row origin
    const int v0 = (tt & 7) * 16;    // out-col origin

    const int tid  = threadIdx.x;
    const int lane = tid & 63;
    const int wid  = tid >> 6;
    const int wm   = wid >> 2;       // 0..1 : pixel-row block
    const int wn   = wid & 3;        // 0..3 : oc block
    const int g    = lane >> 4;      // 0..3 : k-group
    const int wq   = lane & 15;

    // blur item: channel chl (0..31 within chunk), col-pair a -> cols 2a,2a+1 (+col 32 for a=15)
    const int a   = tid & 15;
    const int chl = tid >> 4;
    const int c0  = 2 * a;
    const int wc  = 2 * v0 - 2 + c0;             // global x col of window float 0
    const bool edge = (v0 == 0 && a == 0) || (v0 == 112 && a == 15);
    const float* planeBase = x + (size_t)(n * 128 + chl) * 65536;
    const int xr0 = 2 * u0 - 2;

    // LDS byte offsets (row 0) for this thread's 2-3 output columns
    const unsigned chpart = (unsigned)(((chl >> 1) & 3) * 4 + (chl & 1) * 2);
    const unsigned q4 = (unsigned)(chl >> 3);
    const unsigned o0 = (unsigned)(c0 + 0) * 80u + ((q4 ^ (((unsigned)(c0 + 0) >> 3) & 3u)) << 4) + chpart;
    const unsigned o1 = (unsigned)(c0 + 1) * 80u + ((q4 ^ (((unsigned)(c0 + 1) >> 3) & 3u)) << 4) + chpart;
    const unsigned o2 = (unsigned)(c0 + 2) * 80u + ((q4 ^ (((unsigned)(c0 + 2) >> 3) & 3u)) << 4) + chpart;

    // weights pointer (verified layout)
    const unsigned short* wpL = wp + (size_t)(wn * 64 + wq) * 32 + g * 8;

    f32x4 acc[4][4];
    #pragma unroll
    for (int i = 0; i < 4; ++i)
        #pragma unroll
        for (int j = 0; j < 4; ++j)
            acc[i][j] = (f32x4){0.f, 0.f, 0.f, 0.f};

    for (int ch = 0; ch < 4; ++ch) {
        const float* q = planeBase + (size_t)ch * 32 * 65536 + wc;
        float hA[4], hB[4], hC[4];
        // rows 0-2: loads + horizontal blur only (no LDS writes) -> issue before barrier
        if (!edge) { FROW(0) FROW(1) FROW(2) }
        else       { SROW(0) SROW(1) SROW(2) }
        __syncthreads();   // prev chunk's MFMA reads done before we overwrite blurred
        if (!edge) {
            #pragma unroll
            for (int row = 3; row < 20; ++row) { FROW(row) VROW(row) }
        } else {
            #pragma unroll
            for (int row = 3; row < 20; ++row) { SROW(row) VROW(row) }
        }
        __syncthreads();   // blurred tile complete
        // ---- MFMA stage: 3x3 taps, unroll 1 to cap live registers ----
        const unsigned short* wpc = wpL + (size_t)ch * 9 * 8192;
        #pragma unroll 1
        for (int r = 0; r < 3; ++r) {
            #pragma unroll 1
            for (int s = 0; s < 3; ++s) {
                bf16x8 b0 = *(const bf16x8*)(wpc + 0 * 512);
                bf16x8 b1 = *(const bf16x8*)(wpc + 1 * 512);
                bf16x8 b2 = *(const bf16x8*)(wpc + 2 * 512);
                bf16x8 b3 = *(const bf16x8*)(wpc + 3 * 512);
                wpc += 8192;
                int bj = 2 * wq + s;
                unsigned cb = (unsigned)bj * 80u
                            + ((unsigned)(g ^ ((bj >> 3) & 3)) << 4);
                #pragma unroll
                for (int mf = 0; mf < 4; ++mf) {
                    int bi = 2 * (wm * 4 + mf) + r;
                    bf16x8 afrag = *(const bf16x8*)(lds + (unsigned)bi * 2640u + cb);
                    acc[mf][0] = __builtin_amdgcn_mfma_f32_16x16x32_bf16(afrag, b0, acc[mf][0], 0, 0, 0);
                    acc[mf][1] = __builtin_amdgcn_mfma_f32_16x16x32_bf16(afrag, b1, acc[mf][1], 0, 0, 0);
                    acc[mf][2] = __builtin_amdgcn_mfma_f32_16x16x32_bf16(afrag, b2, acc[mf][2], 0, 0, 0);
                    acc[mf][3] = __builtin_amdgcn_mfma_f32_16x16x32_bf16(afrag, b3, acc[mf][3], 0, 0, 0);
                }
            }
        }
    }

    // ---- epilogue: direct coalesced stores (u = u0+wm*4+mf, v = v0+4g+i, oc = wn*64+nf*16+wq) ----
    const float gain = 1.4142135623730951f;   // sqrt(2)
    #pragma unroll
    for (int nf = 0; nf < 4; ++nf) {
        int ocg = wn * 64 + nf * 16 + wq;
        float bv = bias[ocg];                 // LR_MUL = 1
        #pragma unroll
        for (int mf = 0; mf < 4; ++mf) {
            int u = u0 + wm * 4 + mf;
            f32x4 o;
            #pragma unroll
            for (int i = 0; i < 4; ++i) {
                float z = acc[mf][nf][i] + bv;
                z = (z >= 0.f ? z : 0.2f * z) * gain;
                o[i] = fminf(fmaxf(z, -256.f), 256.f);
            }
            *(f32x4*)(out + (((size_t)n * 256 + ocg) * 128 + u) * 128 + v0 + 4 * g) = o;
        }
    }
}

extern "C" void kernel_launch(void* const* d_in, const int* in_sizes, int n_in,
                              void* d_out, int out_size, void* d_ws, size_t ws_size,
                              hipStream_t stream) {
    const float* x    = (const float*)d_in[0];
    const float* w    = (const float*)d_in[1];
    const float* bias = (const float*)d_in[2];
    unsigned short* wp = (unsigned short*)d_ws;   // 589,824 B
    float* out = (float*)d_out;

    prep_weights<<<1152, 256, 0, stream>>>(w, wp);
    conv_blur_mfma<<<2048, 512, 0, stream>>>(x, wp, bias, out);
}